// Round 3
// baseline (470.776 us; speedup 1.0000x reference)
//
#include <hip/hip_runtime.h>

// SpikeLayer: V_t = reset(V_{t-1} + I_t), reset(x) = (|x|>1 ? 0 : x)
// inputs: [T*B, D] fp32, T=16, B=512, D=8192. out_t = V_t, same shape.
//
// R1 post-mortem: VGPR=24 -> compiler serialized the t-loop (1 outstanding
// load/thread), latency-bound at 2.3 TB/s. Fix: the 16 loads are address-
// independent (only V is a serial chain) -> hoist all 16 float4 loads into
// registers first (16x MLP per thread), then run the chain + stores.
// R2 fix: __builtin_nontemporal_store needs a native clang vector type,
// not HIP_vector_type -> use ext_vector_type(4) float.

constexpr int TIMES = 16;
constexpr long long STEP_F4 = (512LL * 8192LL) / 4;  // float4 elems per t-slice

typedef float f32x4 __attribute__((ext_vector_type(4)));

__global__ __launch_bounds__(256) void SpikeLayer_88553635709313_kernel(
    const f32x4* __restrict__ in, f32x4* __restrict__ out) {
    const long long idx = (long long)blockIdx.x * blockDim.x + threadIdx.x;

    f32x4 I[TIMES];
#pragma unroll
    for (int t = 0; t < TIMES; ++t) {
        I[t] = in[idx + (long long)t * STEP_F4];   // 16 independent loads in flight
    }

    f32x4 V = (f32x4)(0.f, 0.f, 0.f, 0.f);
#pragma unroll
    for (int t = 0; t < TIMES; ++t) {
        V += I[t];
        V.x = (fabsf(V.x) > 1.0f) ? 0.0f : V.x;
        V.y = (fabsf(V.y) > 1.0f) ? 0.0f : V.y;
        V.z = (fabsf(V.z) > 1.0f) ? 0.0f : V.z;
        V.w = (fabsf(V.w) > 1.0f) ? 0.0f : V.w;
        __builtin_nontemporal_store(V, &out[idx + (long long)t * STEP_F4]);
    }
}

extern "C" void kernel_launch(void* const* d_in, const int* in_sizes, int n_in,
                              void* d_out, int out_size, void* d_ws, size_t ws_size,
                              hipStream_t stream) {
    const f32x4* in = (const f32x4*)d_in[0];
    f32x4* out = (f32x4*)d_out;
    const int threads = 256;
    const int blocks = (int)(STEP_F4 / threads);  // 4096
    SpikeLayer_88553635709313_kernel<<<blocks, threads, 0, stream>>>(in, out);
}